// Round 1
// baseline (970.487 us; speedup 1.0000x reference)
//
#include <hip/hip_runtime.h>
#include <hip/hip_bf16.h>

// ---------- helpers for templated Y storage (float or bf16) ----------
__device__ __forceinline__ float toF(float x) { return x; }
__device__ __forceinline__ float toF(__hip_bfloat16 x) { return __bfloat162float(x); }
__device__ __forceinline__ void storeT(float* p, float v) { *p = v; }
__device__ __forceinline__ void storeT(__hip_bfloat16* p, float v) { *p = __float2bfloat16(v); }

// ---------------------------------------------------------------------
// transform: Y[n,k,o] = sum_d X[n,d] * W[k,d,o]
// grid: (ceil(N/128), K2), block 256. Thread (o=t&63, ng=t>>6) owns 32 nodes.
// ---------------------------------------------------------------------
template <typename T>
__global__ __launch_bounds__(256) void transform_kernel(
    const float* __restrict__ X, const float* __restrict__ W,
    T* __restrict__ Y, int N, int K2) {
  __shared__ float Ws[64 * 64];     // W[k] as [d][o]
  __shared__ float XsT[64 * 132];   // x tile transposed: [d][node], pad 128->132
  const int t = threadIdx.x;
  const int k = blockIdx.y;
  const int n0 = blockIdx.x * 128;

  const float* Wk = W + (size_t)k * 4096;
  for (int i = t; i < 1024; i += 256)
    ((float4*)Ws)[i] = ((const float4*)Wk)[i];
  for (int i = t; i < 8192; i += 256) {
    int nl = i >> 6, d = i & 63;
    int n = n0 + nl;
    XsT[d * 132 + nl] = (n < N) ? X[(size_t)n * 64 + d] : 0.f;
  }
  __syncthreads();

  const int o = t & 63, ng = t >> 6;
  float acc[32];
#pragma unroll
  for (int j = 0; j < 32; ++j) acc[j] = 0.f;

  for (int d = 0; d < 64; ++d) {
    float w = Ws[d * 64 + o];
    const float4* xp = (const float4*)&XsT[d * 132 + ng * 32];
#pragma unroll
    for (int j4 = 0; j4 < 8; ++j4) {
      float4 xv = xp[j4];
      acc[j4 * 4 + 0] += xv.x * w;
      acc[j4 * 4 + 1] += xv.y * w;
      acc[j4 * 4 + 2] += xv.z * w;
      acc[j4 * 4 + 3] += xv.w * w;
    }
  }

#pragma unroll
  for (int j = 0; j < 32; ++j) {
    int n = n0 + ng * 32 + j;
    if (n < N) storeT(&Y[((size_t)n * K2 + k) * 64 + o], acc[j]);
  }
}

// ---------------------------------------------------------------------
// degree count: cnt[dst] += 1 per edge (float counts; exact to 2^24)
// ---------------------------------------------------------------------
__global__ __launch_bounds__(256) void count_kernel(
    const int* __restrict__ dst, float* __restrict__ cnt, int nE) {
  int e = blockIdx.x * 256 + threadIdx.x;
  if (e < nE) atomicAdd(&cnt[dst[e]], 1.0f);
}

// ---------------------------------------------------------------------
// edge gather + scatter: one 64-lane wave per edge (4 edges / block)
// m[e,o] = sum_s B_s * Y[src, WI_s, o];  msum[dst,o] += m
// ---------------------------------------------------------------------
template <typename T, int K, int K2>
__global__ __launch_bounds__(256) void edge_kernel(
    const int* __restrict__ src, const int* __restrict__ dst,
    const float* __restrict__ attr, const T* __restrict__ Y,
    float* __restrict__ msum, int nE) {
  int t = threadIdx.x;
  int e = blockIdx.x * 4 + (t >> 6);
  if (e >= nE) return;
  int o = t & 63;
  int s = src[e], d = dst[e];
  float u = attr[2 * e + 0] * (float)(K - 1);
  float v = attr[2 * e + 1] * (float)(K - 1);
  float lf0 = floorf(u), lf1 = floorf(v);
  float f0 = u - lf0, f1 = v - lf1;
  int l0 = (int)lf0, l1 = (int)lf1;
  int i00 = min(max(l0, 0), K - 1), i01 = min(max(l0 + 1, 0), K - 1);
  int i10 = min(max(l1, 0), K - 1), i11 = min(max(l1 + 1, 0), K - 1);
  const T* Yb = Y + (size_t)s * (K2 * 64) + o;
  float m = (1.f - f0) * (1.f - f1) * toF(Yb[(i00 + i10 * K) * 64])
          + (1.f - f0) * f1         * toF(Yb[(i00 + i11 * K) * 64])
          + f0 * (1.f - f1)         * toF(Yb[(i01 + i10 * K) * 64])
          + f0 * f1                 * toF(Yb[(i01 + i11 * K) * 64]);
  atomicAdd(&msum[(size_t)d * 64 + o], m);
}

// ---------------------------------------------------------------------
// node epilogue / dense layer:
// out[n,o] = act( X[n,:]@Wm[:,o] + bias[o] (+ msum[n,o]/max(cnt,1)) )
// ACT: 0=ELU, 1=ReLU. Same tile structure as transform.
// ---------------------------------------------------------------------
template <int ACT, bool AGGR>
__global__ __launch_bounds__(256) void node_dense_kernel(
    const float* __restrict__ X, const float* __restrict__ Wm,
    const float* __restrict__ bias, const float* __restrict__ msum,
    const float* __restrict__ cnt, float* __restrict__ out, int N) {
  __shared__ float Ws[64 * 64];
  __shared__ float XsT[64 * 132];
  const int t = threadIdx.x;
  const int n0 = blockIdx.x * 128;

  for (int i = t; i < 1024; i += 256)
    ((float4*)Ws)[i] = ((const float4*)Wm)[i];
  for (int i = t; i < 8192; i += 256) {
    int nl = i >> 6, d = i & 63;
    int n = n0 + nl;
    XsT[d * 132 + nl] = (n < N) ? X[(size_t)n * 64 + d] : 0.f;
  }
  __syncthreads();

  const int o = t & 63, ng = t >> 6;
  float acc[32];
#pragma unroll
  for (int j = 0; j < 32; ++j) acc[j] = 0.f;

  for (int d = 0; d < 64; ++d) {
    float w = Ws[d * 64 + o];
    const float4* xp = (const float4*)&XsT[d * 132 + ng * 32];
#pragma unroll
    for (int j4 = 0; j4 < 8; ++j4) {
      float4 xv = xp[j4];
      acc[j4 * 4 + 0] += xv.x * w;
      acc[j4 * 4 + 1] += xv.y * w;
      acc[j4 * 4 + 2] += xv.z * w;
      acc[j4 * 4 + 3] += xv.w * w;
    }
  }

  float b = bias[o];
#pragma unroll
  for (int j = 0; j < 32; ++j) {
    int n = n0 + ng * 32 + j;
    if (n >= N) continue;
    float v = acc[j] + b;
    if (AGGR) {
      float c = cnt[n];
      c = c < 1.f ? 1.f : c;
      v += msum[(size_t)n * 64 + o] / c;
    }
    if (ACT == 0) v = v > 0.f ? v : (expf(v) - 1.f);
    else          v = v > 0.f ? v : 0.f;
    out[(size_t)n * 64 + o] = v;
  }
}

// ---------------------------------------------------------------------
// final projection D=64 -> C=8 with ReLU
// ---------------------------------------------------------------------
__global__ __launch_bounds__(256) void mlp2_kernel(
    const float* __restrict__ X, const float* __restrict__ W,
    const float* __restrict__ bias, float* __restrict__ out, int N) {
  __shared__ float Ws[512];
  __shared__ float bs[8];
  __shared__ float Xs[32 * 64];
  int t = threadIdx.x;
  int n0 = blockIdx.x * 32;
  if (t < 8) bs[t] = bias[t];
  for (int i = t; i < 512; i += 256) Ws[i] = W[i];
  for (int i = t; i < 512; i += 256) {
    int n = n0 + (i >> 4);
    ((float4*)Xs)[i] = (n < N) ? ((const float4*)(X + (size_t)n * 64))[i & 15]
                               : make_float4(0.f, 0.f, 0.f, 0.f);
  }
  __syncthreads();
  int c = t & 7, nl = t >> 3;
  float acc = bs[c];
  for (int d = 0; d < 64; ++d) acc += Xs[nl * 64 + d] * Ws[d * 8 + c];
  int n = n0 + nl;
  if (n < N) out[(size_t)n * 8 + c] = acc > 0.f ? acc : 0.f;
}

// ---------------------------------------------------------------------
template <typename T>
static void run_pipeline(const float* x, const int* src, const int* dstv,
                         const float* attr, const float* W1, const float* root1,
                         const float* b1, const float* W2, const float* root2,
                         const float* b2, const float* m1w, const float* m1b,
                         const float* m2w, const float* m2b, float* out,
                         float* msum, float* cnt, float* h1, float* h2,
                         float* t1, T* Y, int N, int nE, hipStream_t stream) {
  dim3 blk(256);
  int nb = (N + 127) / 128;
  int eb = (nE + 3) / 4;
  // ----- layer 1 (K=3, K2=9) -----
  transform_kernel<T><<<dim3(nb, 9), blk, 0, stream>>>(x, W1, Y, N, 9);
  edge_kernel<T, 3, 9><<<eb, blk, 0, stream>>>(src, dstv, attr, Y, msum, nE);
  node_dense_kernel<0, true><<<nb, blk, 0, stream>>>(x, root1, b1, msum, cnt, h1, N);
  // ----- layer 2 (K=5, K2=25) -----
  hipMemsetAsync(msum, 0, (size_t)N * 64 * sizeof(float), stream);
  transform_kernel<T><<<dim3(nb, 25), blk, 0, stream>>>(h1, W2, Y, N, 25);
  edge_kernel<T, 5, 25><<<eb, blk, 0, stream>>>(src, dstv, attr, Y, msum, nE);
  node_dense_kernel<0, true><<<nb, blk, 0, stream>>>(h1, root2, b2, msum, cnt, h2, N);
  // ----- MLP head -----
  node_dense_kernel<1, false><<<nb, blk, 0, stream>>>(h2, m1w, m1b, nullptr, nullptr, t1, N);
  mlp2_kernel<<<(N + 31) / 32, blk, 0, stream>>>(t1, m2w, m2b, out, N);
}

extern "C" void kernel_launch(void* const* d_in, const int* in_sizes, int n_in,
                              void* d_out, int out_size, void* d_ws, size_t ws_size,
                              hipStream_t stream) {
  const float* x     = (const float*)d_in[0];
  const int*   ei    = (const int*)d_in[1];
  const float* attr  = (const float*)d_in[2];
  const float* W1    = (const float*)d_in[3];
  const float* root1 = (const float*)d_in[4];
  const float* b1    = (const float*)d_in[5];
  const float* W2    = (const float*)d_in[6];
  const float* root2 = (const float*)d_in[7];
  const float* b2    = (const float*)d_in[8];
  const float* m1w   = (const float*)d_in[9];
  const float* m1b   = (const float*)d_in[10];
  const float* m2w   = (const float*)d_in[11];
  const float* m2b   = (const float*)d_in[12];

  const int N  = in_sizes[0] / 64;
  const int nE = in_sizes[1] / 2;
  const int* src  = ei;
  const int* dstv = ei + nE;
  float* out = (float*)d_out;

  // workspace layout
  float* msum = (float*)d_ws;                 // N*64
  float* cnt  = msum + (size_t)N * 64;        // N
  float* h1   = cnt + N;                      // N*64
  float* h2   = h1 + (size_t)N * 64;          // N*64
  float* t1   = h2 + (size_t)N * 64;          // N*64
  void*  Yv   = (void*)(t1 + (size_t)N * 64); // up to 25*N*64 (float or bf16)

  size_t base_bytes = ((size_t)N * 64 * 4 + N) * sizeof(float);
  size_t y_f32      = (size_t)25 * N * 64 * sizeof(float);

  // zero msum+cnt (contiguous), then count degrees once (same graph both layers)
  hipMemsetAsync(msum, 0, ((size_t)N * 64 + N) * sizeof(float), stream);
  count_kernel<<<(nE + 255) / 256, 256, 0, stream>>>(dstv, cnt, nE);

  if (ws_size >= base_bytes + y_f32) {
    run_pipeline<float>(x, src, dstv, attr, W1, root1, b1, W2, root2, b2,
                        m1w, m1b, m2w, m2b, out, msum, cnt, h1, h2, t1,
                        (float*)Yv, N, nE, stream);
  } else {
    run_pipeline<__hip_bfloat16>(x, src, dstv, attr, W1, root1, b1, W2, root2, b2,
                                 m1w, m1b, m2w, m2b, out, msum, cnt, h1, h2, t1,
                                 (__hip_bfloat16*)Yv, N, nE, stream);
  }
}

// Round 3
// 673.129 us; speedup vs baseline: 1.4418x; 1.4418x over previous
//
#include <hip/hip_runtime.h>
#include <hip/hip_bf16.h>

typedef __attribute__((ext_vector_type(8))) short short8;
typedef __attribute__((ext_vector_type(4))) float floatx4;

__device__ __forceinline__ unsigned short f2bf(float x) {
  __hip_bfloat16 h = __float2bfloat16(x);
  return __builtin_bit_cast(unsigned short, h);
}

// ---------------------------------------------------------------------
// pre-transpose + convert W: W[k][d][o] (fp32) -> Wt[k][o][d] (bf16)
// ---------------------------------------------------------------------
__global__ __launch_bounds__(256) void cvt_wt_kernel(
    const float* __restrict__ W, __hip_bfloat16* __restrict__ Wt, int K2) {
  int i = blockIdx.x * 256 + threadIdx.x;   // k*4096 + o*64 + d
  if (i >= K2 * 4096) return;
  int k = i >> 12, r = i & 4095, o = r >> 6, d = r & 63;
  Wt[i] = __float2bfloat16(W[(k << 12) + (d << 6) + o]);
}

// ---------------------------------------------------------------------
// MFMA transform: Y[n,k,o] = sum_d X[n,d] * W[k,d,o]  (bf16 in, bf16 out,
// fp32 accumulate). Block = 256 thr (4 waves), 64 nodes/block, loops all k.
// LDS rows padded 64->72 shorts to break b128 row-stride bank conflicts.
// ---------------------------------------------------------------------
template <int K2>
__global__ __launch_bounds__(256) void transform_mfma(
    const float* __restrict__ X, const __hip_bfloat16* __restrict__ Wt,
    __hip_bfloat16* __restrict__ Y, int N) {
  __shared__ unsigned short Xs[64 * 72];
  __shared__ unsigned short Ws[64 * 72];
  const int t = threadIdx.x;
  const int n0 = blockIdx.x * 64;

  // stage X tile, converting fp32->bf16. chunk i: node i>>3, d = (i&7)*8
  for (int i = t; i < 512; i += 256) {
    int node = n0 + (i >> 3);
    int dbase = (i & 7) * 8;
    unsigned short pk[8];
    if (node < N) {
      const float* xp = X + (size_t)node * 64 + dbase;
#pragma unroll
      for (int j = 0; j < 8; ++j) pk[j] = f2bf(xp[j]);
    } else {
#pragma unroll
      for (int j = 0; j < 8; ++j) pk[j] = 0;
    }
    *(float4*)&Xs[(i >> 3) * 72 + dbase] = *(float4*)pk;
  }
  __syncthreads();

  const int lane = t & 63, w = t >> 6;
  const int mrow = lane & 15, q = lane >> 4;

  // A fragments: A[m][k] with m=lane&15, k=q*8+j (16B aligned, row pad 72)
  short8 a0 = *(const short8*)&Xs[(w * 16 + mrow) * 72 + q * 8];
  short8 a1 = *(const short8*)&Xs[(w * 16 + mrow) * 72 + 32 + q * 8];

  for (int k = 0; k < K2; ++k) {
    __syncthreads();  // previous iter's readers done with Ws
    const float4* wsrc = (const float4*)(Wt + (size_t)k * 4096);
    for (int i = t; i < 512; i += 256)
      *(float4*)&Ws[(i >> 3) * 72 + (i & 7) * 8] = wsrc[i];
    __syncthreads();

    floatx4 acc[4] = {{0,0,0,0},{0,0,0,0},{0,0,0,0},{0,0,0,0}};
#pragma unroll
    for (int ot = 0; ot < 4; ++ot) {
      short8 b0 = *(const short8*)&Ws[(ot * 16 + mrow) * 72 + q * 8];
      short8 b1 = *(const short8*)&Ws[(ot * 16 + mrow) * 72 + 32 + q * 8];
      acc[ot] = __builtin_amdgcn_mfma_f32_16x16x32_bf16(a0, b0, acc[ot], 0, 0, 0);
      acc[ot] = __builtin_amdgcn_mfma_f32_16x16x32_bf16(a1, b1, acc[ot], 0, 0, 0);
    }

    // C/D layout: o = ot*16 + (lane&15), node = w*16 + q*4 + reg
#pragma unroll
    for (int ot = 0; ot < 4; ++ot) {
#pragma unroll
      for (int r = 0; r < 4; ++r) {
        int node = n0 + w * 16 + q * 4 + r;
        if (node < N)
          Y[((size_t)node * K2 + k) * 64 + ot * 16 + mrow] =
              __float2bfloat16(acc[ot][r]);
      }
    }
  }
}

// ---------------------------------------------------------------------
// degree count
// ---------------------------------------------------------------------
__global__ __launch_bounds__(256) void count_kernel(
    const int* __restrict__ dst, float* __restrict__ cnt, int nE) {
  int e = blockIdx.x * 256 + threadIdx.x;
  if (e < nE) atomicAdd(&cnt[dst[e]], 1.0f);
}

// ---------------------------------------------------------------------
// edge gather + scatter: one 64-lane wave per edge (4 edges / block)
// ---------------------------------------------------------------------
template <int K, int K2>
__global__ __launch_bounds__(256) void edge_kernel(
    const int* __restrict__ src, const int* __restrict__ dst,
    const float* __restrict__ attr, const __hip_bfloat16* __restrict__ Y,
    float* __restrict__ msum, int nE) {
  int t = threadIdx.x;
  int e = blockIdx.x * 4 + (t >> 6);
  if (e >= nE) return;
  int o = t & 63;
  int s = src[e], d = dst[e];
  float u = attr[2 * e + 0] * (float)(K - 1);
  float v = attr[2 * e + 1] * (float)(K - 1);
  float lf0 = floorf(u), lf1 = floorf(v);
  float f0 = u - lf0, f1 = v - lf1;
  int l0 = (int)lf0, l1 = (int)lf1;
  int i00 = min(max(l0, 0), K - 1), i01 = min(max(l0 + 1, 0), K - 1);
  int i10 = min(max(l1, 0), K - 1), i11 = min(max(l1 + 1, 0), K - 1);
  const __hip_bfloat16* Yb = Y + (size_t)s * (K2 * 64) + o;
  float m = (1.f - f0) * (1.f - f1) * __bfloat162float(Yb[(i00 + i10 * K) * 64])
          + (1.f - f0) * f1         * __bfloat162float(Yb[(i00 + i11 * K) * 64])
          + f0 * (1.f - f1)         * __bfloat162float(Yb[(i01 + i10 * K) * 64])
          + f0 * f1                 * __bfloat162float(Yb[(i01 + i11 * K) * 64]);
  atomicAdd(&msum[(size_t)d * 64 + o], m);
}

// ---------------------------------------------------------------------
// node epilogue / dense layer (fp32 VALU; small cost):
// out[n,o] = act( X[n,:]@Wm[:,o] + bias[o] (+ msum[n,o]/max(cnt,1)) )
// ---------------------------------------------------------------------
template <int ACT, bool AGGR>
__global__ __launch_bounds__(256) void node_dense_kernel(
    const float* __restrict__ X, const float* __restrict__ Wm,
    const float* __restrict__ bias, const float* __restrict__ msum,
    const float* __restrict__ cnt, float* __restrict__ out, int N) {
  __shared__ float Ws[64 * 64];
  __shared__ float XsT[64 * 132];
  const int t = threadIdx.x;
  const int n0 = blockIdx.x * 128;

  for (int i = t; i < 1024; i += 256)
    ((float4*)Ws)[i] = ((const float4*)Wm)[i];
  for (int i = t; i < 8192; i += 256) {
    int nl = i >> 6, d = i & 63;
    int n = n0 + nl;
    XsT[d * 132 + nl] = (n < N) ? X[(size_t)n * 64 + d] : 0.f;
  }
  __syncthreads();

  const int o = t & 63, ng = t >> 6;
  float acc[32];
#pragma unroll
  for (int j = 0; j < 32; ++j) acc[j] = 0.f;

  for (int d = 0; d < 64; ++d) {
    float w = Ws[d * 64 + o];
    const float4* xp = (const float4*)&XsT[d * 132 + ng * 32];
#pragma unroll
    for (int j4 = 0; j4 < 8; ++j4) {
      float4 xv = xp[j4];
      acc[j4 * 4 + 0] += xv.x * w;
      acc[j4 * 4 + 1] += xv.y * w;
      acc[j4 * 4 + 2] += xv.z * w;
      acc[j4 * 4 + 3] += xv.w * w;
    }
  }

  float b = bias[o];
#pragma unroll
  for (int j = 0; j < 32; ++j) {
    int n = n0 + ng * 32 + j;
    if (n >= N) continue;
    float v = acc[j] + b;
    if (AGGR) {
      float c = cnt[n];
      c = c < 1.f ? 1.f : c;
      v += msum[(size_t)n * 64 + o] / c;
    }
    if (ACT == 0) v = v > 0.f ? v : (expf(v) - 1.f);
    else          v = v > 0.f ? v : 0.f;
    out[(size_t)n * 64 + o] = v;
  }
}

// ---------------------------------------------------------------------
// final projection D=64 -> C=8 with ReLU
// ---------------------------------------------------------------------
__global__ __launch_bounds__(256) void mlp2_kernel(
    const float* __restrict__ X, const float* __restrict__ W,
    const float* __restrict__ bias, float* __restrict__ out, int N) {
  __shared__ float Ws[512];
  __shared__ float bs[8];
  __shared__ float Xs[32 * 64];
  int t = threadIdx.x;
  int n0 = blockIdx.x * 32;
  if (t < 8) bs[t] = bias[t];
  for (int i = t; i < 512; i += 256) Ws[i] = W[i];
  for (int i = t; i < 512; i += 256) {
    int n = n0 + (i >> 4);
    ((float4*)Xs)[i] = (n < N) ? ((const float4*)(X + (size_t)n * 64))[i & 15]
                               : make_float4(0.f, 0.f, 0.f, 0.f);
  }
  __syncthreads();
  int c = t & 7, nl = t >> 3;
  float acc = bs[c];
  for (int d = 0; d < 64; ++d) acc += Xs[nl * 64 + d] * Ws[d * 8 + c];
  int n = n0 + nl;
  if (n < N) out[(size_t)n * 8 + c] = acc > 0.f ? acc : 0.f;
}

// ---------------------------------------------------------------------
extern "C" void kernel_launch(void* const* d_in, const int* in_sizes, int n_in,
                              void* d_out, int out_size, void* d_ws, size_t ws_size,
                              hipStream_t stream) {
  const float* x     = (const float*)d_in[0];
  const int*   ei    = (const int*)d_in[1];
  const float* attr  = (const float*)d_in[2];
  const float* W1    = (const float*)d_in[3];
  const float* root1 = (const float*)d_in[4];
  const float* b1    = (const float*)d_in[5];
  const float* W2    = (const float*)d_in[6];
  const float* root2 = (const float*)d_in[7];
  const float* b2    = (const float*)d_in[8];
  const float* m1w   = (const float*)d_in[9];
  const float* m1b   = (const float*)d_in[10];
  const float* m2w   = (const float*)d_in[11];
  const float* m2b   = (const float*)d_in[12];

  const int N  = in_sizes[0] / 64;
  const int nE = in_sizes[1] / 2;
  const int* src  = ei;
  const int* dstv = ei + nE;
  float* out = (float*)d_out;

  // workspace layout (fp32 section, then bf16 section)
  float* msum = (float*)d_ws;                 // N*64
  float* cnt  = msum + (size_t)N * 64;        // N
  float* h1   = cnt + N;                      // N*64
  float* h2   = h1 + (size_t)N * 64;          // N*64
  float* t1   = h2 + (size_t)N * 64;          // N*64
  __hip_bfloat16* W1t = (__hip_bfloat16*)(t1 + (size_t)N * 64);  // 9*4096
  __hip_bfloat16* W2t = W1t + 9 * 4096;                          // 25*4096
  __hip_bfloat16* Y   = W2t + 25 * 4096;                         // 25*N*64

  dim3 blk(256);
  int nb128 = (N + 127) / 128;
  int nb64  = (N + 63) / 64;
  int eb    = (nE + 3) / 4;

  // weight prep + degree count (graph identical both layers)
  cvt_wt_kernel<<<(9 * 4096 + 255) / 256, blk, 0, stream>>>(W1, W1t, 9);
  cvt_wt_kernel<<<(25 * 4096 + 255) / 256, blk, 0, stream>>>(W2, W2t, 25);
  (void)hipMemsetAsync(msum, 0, ((size_t)N * 64 + N) * sizeof(float), stream);
  count_kernel<<<(nE + 255) / 256, blk, 0, stream>>>(dstv, cnt, nE);

  // ----- layer 1 (K=3, K2=9) -----
  transform_mfma<9><<<nb64, blk, 0, stream>>>(x, W1t, Y, N);
  edge_kernel<3, 9><<<eb, blk, 0, stream>>>(src, dstv, attr, Y, msum, nE);
  node_dense_kernel<0, true><<<nb128, blk, 0, stream>>>(x, root1, b1, msum, cnt, h1, N);

  // ----- layer 2 (K=5, K2=25) -----
  transform_mfma<25><<<nb64, blk, 0, stream>>>(h1, W2t, Y, N);
  (void)hipMemsetAsync(msum, 0, (size_t)N * 64 * sizeof(float), stream);
  edge_kernel<5, 25><<<eb, blk, 0, stream>>>(src, dstv, attr, Y, msum, nE);
  node_dense_kernel<0, true><<<nb128, blk, 0, stream>>>(h1, root2, b2, msum, cnt, h2, N);

  // ----- MLP head -----
  node_dense_kernel<1, false><<<nb128, blk, 0, stream>>>(h2, m1w, m1b, nullptr, nullptr, t1, N);
  mlp2_kernel<<<(N + 31) / 32, blk, 0, stream>>>(t1, m2w, m2b, out, N);
}

// Round 4
// 670.156 us; speedup vs baseline: 1.4482x; 1.0044x over previous
//
#include <hip/hip_runtime.h>
#include <hip/hip_bf16.h>

typedef __attribute__((ext_vector_type(8))) short short8;
typedef __attribute__((ext_vector_type(4))) float floatx4;

__device__ __forceinline__ unsigned short f2bf(float x) {
  __hip_bfloat16 h = __float2bfloat16(x);
  return __builtin_bit_cast(unsigned short, h);
}

// ---------------------------------------------------------------------
// pre-transpose + convert W: W[k][d][o] (fp32) -> Wt[k][o][d] (bf16)
// ---------------------------------------------------------------------
__global__ __launch_bounds__(256) void cvt_wt_kernel(
    const float* __restrict__ W, __hip_bfloat16* __restrict__ Wt, int K2) {
  int i = blockIdx.x * 256 + threadIdx.x;   // k*4096 + o*64 + d
  if (i >= K2 * 4096) return;
  int k = i >> 12, r = i & 4095, o = r >> 6, d = r & 63;
  Wt[i] = __float2bfloat16(W[(k << 12) + (d << 6) + o]);
}

// ---------------------------------------------------------------------
// MFMA transform: Y[n,k,o] = sum_d X[n,d] * W[k,d,o]  (bf16 in/out, fp32 acc)
// ---------------------------------------------------------------------
template <int K2>
__global__ __launch_bounds__(256) void transform_mfma(
    const float* __restrict__ X, const __hip_bfloat16* __restrict__ Wt,
    __hip_bfloat16* __restrict__ Y, int N) {
  __shared__ unsigned short Xs[64 * 72];
  __shared__ unsigned short Ws[64 * 72];
  const int t = threadIdx.x;
  const int n0 = blockIdx.x * 64;

  for (int i = t; i < 512; i += 256) {
    int node = n0 + (i >> 3);
    int dbase = (i & 7) * 8;
    unsigned short pk[8];
    if (node < N) {
      const float* xp = X + (size_t)node * 64 + dbase;
#pragma unroll
      for (int j = 0; j < 8; ++j) pk[j] = f2bf(xp[j]);
    } else {
#pragma unroll
      for (int j = 0; j < 8; ++j) pk[j] = 0;
    }
    *(float4*)&Xs[(i >> 3) * 72 + dbase] = *(float4*)pk;
  }
  __syncthreads();

  const int lane = t & 63, w = t >> 6;
  const int mrow = lane & 15, q = lane >> 4;

  short8 a0 = *(const short8*)&Xs[(w * 16 + mrow) * 72 + q * 8];
  short8 a1 = *(const short8*)&Xs[(w * 16 + mrow) * 72 + 32 + q * 8];

  for (int k = 0; k < K2; ++k) {
    __syncthreads();
    const float4* wsrc = (const float4*)(Wt + (size_t)k * 4096);
    for (int i = t; i < 512; i += 256)
      *(float4*)&Ws[(i >> 3) * 72 + (i & 7) * 8] = wsrc[i];
    __syncthreads();

    floatx4 acc[4] = {{0,0,0,0},{0,0,0,0},{0,0,0,0},{0,0,0,0}};
#pragma unroll
    for (int ot = 0; ot < 4; ++ot) {
      short8 b0 = *(const short8*)&Ws[(ot * 16 + mrow) * 72 + q * 8];
      short8 b1 = *(const short8*)&Ws[(ot * 16 + mrow) * 72 + 32 + q * 8];
      acc[ot] = __builtin_amdgcn_mfma_f32_16x16x32_bf16(a0, b0, acc[ot], 0, 0, 0);
      acc[ot] = __builtin_amdgcn_mfma_f32_16x16x32_bf16(a1, b1, acc[ot], 0, 0, 0);
    }

#pragma unroll
    for (int ot = 0; ot < 4; ++ot) {
#pragma unroll
      for (int r = 0; r < 4; ++r) {
        int node = n0 + w * 16 + q * 4 + r;
        if (node < N)
          Y[((size_t)node * K2 + k) * 64 + ot * 16 + mrow] =
              __float2bfloat16(acc[ot][r]);
      }
    }
  }
}

// ---------------------------------------------------------------------
// CSR build: histogram -> 3-step exclusive scan -> cursor scatter
// ---------------------------------------------------------------------
__global__ __launch_bounds__(256) void zero_int_kernel(int* __restrict__ p, int n) {
  int i = blockIdx.x * 256 + threadIdx.x;
  if (i < n) p[i] = 0;
}

__global__ __launch_bounds__(256) void hist_kernel(
    const int* __restrict__ dst, int* __restrict__ deg, int nE) {
  int e = blockIdx.x * 256 + threadIdx.x;
  if (e < nE) atomicAdd(&deg[dst[e]], 1);
}

__global__ __launch_bounds__(256) void blocksum_kernel(
    const int* __restrict__ deg, int* __restrict__ partial, int N) {
  __shared__ int s[256];
  int t = threadIdx.x, i = blockIdx.x * 256 + t;
  s[t] = (i < N) ? deg[i] : 0;
  __syncthreads();
  for (int off = 128; off > 0; off >>= 1) {
    if (t < off) s[t] += s[t + off];
    __syncthreads();
  }
  if (t == 0) partial[blockIdx.x] = s[0];
}

__global__ void scanpartials_kernel(int* __restrict__ partial, int nb) {
  if (threadIdx.x == 0 && blockIdx.x == 0) {
    int run = 0;
    for (int j = 0; j < nb; ++j) { int v = partial[j]; partial[j] = run; run += v; }
  }
}

__global__ __launch_bounds__(256) void blockscan_kernel(
    const int* __restrict__ deg, const int* __restrict__ partial,
    int* __restrict__ row_start, int* __restrict__ cursor, int N, int nE) {
  __shared__ int s[256];
  int t = threadIdx.x, i = blockIdx.x * 256 + t;
  int v = (i < N) ? deg[i] : 0;
  s[t] = v;
  __syncthreads();
  for (int off = 1; off < 256; off <<= 1) {
    int x = (t >= off) ? s[t - off] : 0;
    __syncthreads();
    s[t] += x;
    __syncthreads();
  }
  if (i < N) {
    int excl = s[t] - v + partial[blockIdx.x];
    row_start[i] = excl;
    cursor[i] = excl;
  }
  if (i == 0) row_start[N] = nE;
}

__global__ __launch_bounds__(256) void scatter_kernel(
    const int* __restrict__ dst, int* __restrict__ cursor,
    int* __restrict__ eidx, int nE) {
  int e = blockIdx.x * 256 + threadIdx.x;
  if (e < nE) {
    int pos = atomicAdd(&cursor[dst[e]], 1);
    eidx[pos] = e;
  }
}

// ---------------------------------------------------------------------
// atomic-free aggregation: one wave per dst node, lane o = channel o.
// aggr[n,o] = (1/max(deg,1)) * sum_{e in edges(n)} sum_s B_s Y[src_e, WI_s, o]
// ---------------------------------------------------------------------
template <int K, int K2>
__global__ __launch_bounds__(256) void aggr_kernel(
    const int* __restrict__ eidx, const int* __restrict__ row_start,
    const int* __restrict__ src, const float* __restrict__ attr,
    const __hip_bfloat16* __restrict__ Y, float* __restrict__ aggr, int N) {
  int t = threadIdx.x;
  int node = blockIdx.x * 4 + (t >> 6);
  if (node >= N) return;
  int o = t & 63;
  int beg = row_start[node], end = row_start[node + 1];
  float acc = 0.f;
  for (int j = beg; j < end; ++j) {
    int e = eidx[j];
    int s = src[e];
    float u = attr[2 * e + 0] * (float)(K - 1);
    float v = attr[2 * e + 1] * (float)(K - 1);
    float lf0 = floorf(u), lf1 = floorf(v);
    float f0 = u - lf0, f1 = v - lf1;
    int l0 = (int)lf0, l1 = (int)lf1;
    int i00 = min(max(l0, 0), K - 1), i01 = min(max(l0 + 1, 0), K - 1);
    int i10 = min(max(l1, 0), K - 1), i11 = min(max(l1 + 1, 0), K - 1);
    const __hip_bfloat16* Yb = Y + (size_t)s * (K2 * 64) + o;
    acc += (1.f - f0) * (1.f - f1) * __bfloat162float(Yb[(i00 + i10 * K) * 64])
         + (1.f - f0) * f1         * __bfloat162float(Yb[(i00 + i11 * K) * 64])
         + f0 * (1.f - f1)         * __bfloat162float(Yb[(i01 + i10 * K) * 64])
         + f0 * f1                 * __bfloat162float(Yb[(i01 + i11 * K) * 64]);
  }
  int deg = end - beg;
  float inv = 1.f / (float)max(deg, 1);
  aggr[(size_t)node * 64 + o] = acc * inv;
}

// ---------------------------------------------------------------------
// node epilogue / dense layer: out = act(X@Wm + b (+ aggr))  (aggr pre-divided)
// ---------------------------------------------------------------------
template <int ACT, bool AGGR>
__global__ __launch_bounds__(256) void node_dense_kernel(
    const float* __restrict__ X, const float* __restrict__ Wm,
    const float* __restrict__ bias, const float* __restrict__ aggr,
    float* __restrict__ out, int N) {
  __shared__ float Ws[64 * 64];
  __shared__ float XsT[64 * 132];
  const int t = threadIdx.x;
  const int n0 = blockIdx.x * 128;

  for (int i = t; i < 1024; i += 256)
    ((float4*)Ws)[i] = ((const float4*)Wm)[i];
  for (int i = t; i < 8192; i += 256) {
    int nl = i >> 6, d = i & 63;
    int n = n0 + nl;
    XsT[d * 132 + nl] = (n < N) ? X[(size_t)n * 64 + d] : 0.f;
  }
  __syncthreads();

  const int o = t & 63, ng = t >> 6;
  float acc[32];
#pragma unroll
  for (int j = 0; j < 32; ++j) acc[j] = 0.f;

  for (int d = 0; d < 64; ++d) {
    float w = Ws[d * 64 + o];
    const float4* xp = (const float4*)&XsT[d * 132 + ng * 32];
#pragma unroll
    for (int j4 = 0; j4 < 8; ++j4) {
      float4 xv = xp[j4];
      acc[j4 * 4 + 0] += xv.x * w;
      acc[j4 * 4 + 1] += xv.y * w;
      acc[j4 * 4 + 2] += xv.z * w;
      acc[j4 * 4 + 3] += xv.w * w;
    }
  }

  float b = bias[o];
#pragma unroll
  for (int j = 0; j < 32; ++j) {
    int n = n0 + ng * 32 + j;
    if (n >= N) continue;
    float v = acc[j] + b;
    if (AGGR) v += aggr[(size_t)n * 64 + o];
    if (ACT == 0) v = v > 0.f ? v : (expf(v) - 1.f);
    else          v = v > 0.f ? v : 0.f;
    out[(size_t)n * 64 + o] = v;
  }
}

// ---------------------------------------------------------------------
// final projection D=64 -> C=8 with ReLU
// ---------------------------------------------------------------------
__global__ __launch_bounds__(256) void mlp2_kernel(
    const float* __restrict__ X, const float* __restrict__ W,
    const float* __restrict__ bias, float* __restrict__ out, int N) {
  __shared__ float Ws[512];
  __shared__ float bs[8];
  __shared__ float Xs[32 * 64];
  int t = threadIdx.x;
  int n0 = blockIdx.x * 32;
  if (t < 8) bs[t] = bias[t];
  for (int i = t; i < 512; i += 256) Ws[i] = W[i];
  for (int i = t; i < 512; i += 256) {
    int n = n0 + (i >> 4);
    ((float4*)Xs)[i] = (n < N) ? ((const float4*)(X + (size_t)n * 64))[i & 15]
                               : make_float4(0.f, 0.f, 0.f, 0.f);
  }
  __syncthreads();
  int c = t & 7, nl = t >> 3;
  float acc = bs[c];
  for (int d = 0; d < 64; ++d) acc += Xs[nl * 64 + d] * Ws[d * 8 + c];
  int n = n0 + nl;
  if (n < N) out[(size_t)n * 8 + c] = acc > 0.f ? acc : 0.f;
}

// ---------------------------------------------------------------------
extern "C" void kernel_launch(void* const* d_in, const int* in_sizes, int n_in,
                              void* d_out, int out_size, void* d_ws, size_t ws_size,
                              hipStream_t stream) {
  const float* x     = (const float*)d_in[0];
  const int*   ei    = (const int*)d_in[1];
  const float* attr  = (const float*)d_in[2];
  const float* W1    = (const float*)d_in[3];
  const float* root1 = (const float*)d_in[4];
  const float* b1    = (const float*)d_in[5];
  const float* W2    = (const float*)d_in[6];
  const float* root2 = (const float*)d_in[7];
  const float* b2    = (const float*)d_in[8];
  const float* m1w   = (const float*)d_in[9];
  const float* m1b   = (const float*)d_in[10];
  const float* m2w   = (const float*)d_in[11];
  const float* m2b   = (const float*)d_in[12];

  const int N  = in_sizes[0] / 64;
  const int nE = in_sizes[1] / 2;
  const int* src  = ei;
  const int* dstv = ei + nE;
  float* out = (float*)d_out;

  // workspace layout
  float* aggr = (float*)d_ws;                  // N*64
  float* h1   = aggr + (size_t)N * 64;         // N*64
  float* h2   = h1 + (size_t)N * 64;           // N*64
  float* t1   = h2 + (size_t)N * 64;           // N*64
  int* deg       = (int*)(t1 + (size_t)N * 64);   // N
  int* row_start = deg + N;                       // N+1
  int* cursor    = row_start + (N + 1);           // N
  int* eidx      = cursor + N;                    // nE
  int* partial   = eidx + nE;                     // nb_scan
  __hip_bfloat16* W1t = (__hip_bfloat16*)(partial + 4096);  // 9*4096
  __hip_bfloat16* W2t = W1t + 9 * 4096;                     // 25*4096
  __hip_bfloat16* Y   = W2t + 25 * 4096;                    // 25*N*64

  dim3 blk(256);
  int nb128 = (N + 127) / 128;
  int nb64  = (N + 63) / 64;
  int nbN   = (N + 255) / 256;      // scan blocks
  int nbE   = (nE + 255) / 256;
  int nbAg  = (N + 3) / 4;

  // ----- CSR build (graph identical both layers) -----
  zero_int_kernel<<<nbN, blk, 0, stream>>>(deg, N);
  hist_kernel<<<nbE, blk, 0, stream>>>(dstv, deg, nE);
  blocksum_kernel<<<nbN, blk, 0, stream>>>(deg, partial, N);
  scanpartials_kernel<<<1, 64, 0, stream>>>(partial, nbN);
  blockscan_kernel<<<nbN, blk, 0, stream>>>(deg, partial, row_start, cursor, N, nE);
  scatter_kernel<<<nbE, blk, 0, stream>>>(dstv, cursor, eidx, nE);

  // weight prep
  cvt_wt_kernel<<<(9 * 4096 + 255) / 256, blk, 0, stream>>>(W1, W1t, 9);
  cvt_wt_kernel<<<(25 * 4096 + 255) / 256, blk, 0, stream>>>(W2, W2t, 25);

  // ----- layer 1 (K=3, K2=9) -----
  transform_mfma<9><<<nb64, blk, 0, stream>>>(x, W1t, Y, N);
  aggr_kernel<3, 9><<<nbAg, blk, 0, stream>>>(eidx, row_start, src, attr, Y, aggr, N);
  node_dense_kernel<0, true><<<nb128, blk, 0, stream>>>(x, root1, b1, aggr, h1, N);

  // ----- layer 2 (K=5, K2=25) -----
  transform_mfma<25><<<nb64, blk, 0, stream>>>(h1, W2t, Y, N);
  aggr_kernel<5, 25><<<nbAg, blk, 0, stream>>>(eidx, row_start, src, attr, Y, aggr, N);
  node_dense_kernel<0, true><<<nb128, blk, 0, stream>>>(h1, root2, b2, aggr, h2, N);

  // ----- MLP head -----
  node_dense_kernel<1, false><<<nb128, blk, 0, stream>>>(h2, m1w, m1b, nullptr, t1, N);
  mlp2_kernel<<<(N + 31) / 32, blk, 0, stream>>>(t1, m2w, m2b, out, N);
}